// Round 7
// baseline (264.206 us; speedup 1.0000x reference)
//
#include <hip/hip_runtime.h>
#include <stdint.h>

using f32x4  = __attribute__((ext_vector_type(4))) float;
using bf16x8 = __attribute__((ext_vector_type(8))) short;
using ushort8 = __attribute__((ext_vector_type(8))) unsigned short;

#define B_   16384
#define S_   256
#define DIN  2048
#define DFC  1024
#define NB_  10

// f32 -> bf16 round-to-nearest-even
__device__ __forceinline__ unsigned short f2bf(float f) {
  union { float f; unsigned int u; } v; v.f = f;
  unsigned int u = v.u;
  unsigned int r = (u + 0x7FFFu + ((u >> 16) & 1u)) >> 16;
  return (unsigned short)r;
}

// async global->LDS, 16B per lane. LDS dest is wave-uniform base + lane*16.
__device__ __forceinline__ void gload_lds16(const void* g, void* l) {
  __builtin_amdgcn_global_load_lds(
      (const __attribute__((address_space(1))) unsigned int*)g,
      (__attribute__((address_space(3))) unsigned int*)l, 16, 0, 0);
}

// ---------------- K0: W1 (f32, [K=2048][N=1024]) -> Wt (bf16, [N][K]) ----------------
__global__ __launch_bounds__(256)
void convT_kernel(const float* __restrict__ W, unsigned short* __restrict__ Wt) {
  __shared__ unsigned short t[32][33];
  const int tx = threadIdx.x & 31;
  const int ty = threadIdx.x >> 5;          // 0..7
  const int nb = blockIdx.x * 32;           // n base
  const int kb = blockIdx.y * 32;           // k base
#pragma unroll
  for (int i = 0; i < 32; i += 8)
    t[ty + i][tx] = f2bf(W[(size_t)(kb + ty + i) * DFC + nb + tx]);
  __syncthreads();
#pragma unroll
  for (int i = 0; i < 32; i += 8)
    Wt[(size_t)(nb + ty + i) * DIN + kb + tx] = t[tx][ty + i];
}

// ---------------- K1: x = elu(A @ Wt^T + b1), stored bf16 ----------------
// r2-proven structure: 128x128 tile, BK=64, 4 waves (2x2 of 64x64), single
// LDS buffer, 2 __syncthreads per K-step. NEW: A staged directly as f32 via
// global_load_lds (two [128][32]-f32 slices, 128B rows, 8x16B chunks, XOR
// swizzle chunk p = c ^ (row&7), linear dest + inverse-swizzled source);
// read-side conversion to bf16 via v_cvt_pk_bf16_f32. B staged bf16 as in r2.
__global__ __launch_bounds__(256)
void gemm1_kernel(const float* __restrict__ A, const unsigned short* __restrict__ Bt,
                  const float* __restrict__ b1, unsigned short* __restrict__ X) {
  __shared__ float sAf[2][128 * 32];        // 2 x 16KB f32 (k-halves of BK=64)
  __shared__ unsigned short sB[128 * 64];   // 16KB bf16
  const int tid  = threadIdx.x;
  const int wave = tid >> 6, lane = tid & 63;
  // XCD-chunked swizzle: 8 consecutive slots (sharing one A row-panel) -> same XCD.
  const int b    = blockIdx.x;              // 1024 blocks
  const int xcd  = b & 7, slot = b >> 3;
  const int mtile = xcd * 16 + (slot >> 3); // 0..127
  const int ntile = slot & 7;               // 0..7
  const int rowBase = mtile * 128, colBase = ntile * 128;
  const int wr = wave >> 1, wc = wave & 1;

  f32x4 acc[4][4] = {};

  // staging source mapping (lrow&7 == lane>>3 for all instrs)
  const int srow = wave * 32 + (lane >> 3);           // + i*8 / + j*8 per instr
  const int schk = (lane & 7) ^ (lane >> 3);          // inverse-swizzled chunk
  const float*          gAf = A  + (size_t)(rowBase + srow) * DIN + schk * 4;
  const unsigned short* gBt = Bt + (size_t)(colBase + srow) * DIN + schk * 8;

  // fragment read offsets
  const int frow = lane & 15, hi = lane >> 4;
  const int s7 = frow & 7;
  const int p0q = (2 * hi) ^ s7;                      // A f32 chunk pos (k lo half)

  for (int kk = 0; kk < DIN; kk += 64) {
    // ---- stage: A f32 (2 slices x 4 instrs), B bf16 (4 instrs) ----
#pragma unroll
    for (int j = 0; j < 4; ++j) {
      gload_lds16(gAf + kk + (size_t)j * 8 * DIN,      &sAf[0][(wave * 4 + j) * 256]);
      gload_lds16(gAf + kk + 32 + (size_t)j * 8 * DIN, &sAf[1][(wave * 4 + j) * 256]);
      gload_lds16(gBt + kk + (size_t)j * 8 * DIN,      &sB[(wave * 4 + j) * 512]);
    }
    __syncthreads();
#pragma unroll
    for (int ks = 0; ks < 2; ++ks) {
      bf16x8 afr[4], bfr[4];
      const int rchk = ((ks * 4 + hi) ^ s7) * 8;
#pragma unroll
      for (int n = 0; n < 4; ++n)
        bfr[n] = *(const bf16x8*)&sB[(wc * 64 + n * 16 + frow) * 64 + rchk];
#pragma unroll
      for (int m = 0; m < 4; ++m) {
        const float* s_ = &sAf[ks][(wr * 64 + m * 16 + frow) * 32];
        f32x4 v0 = *(const f32x4*)(s_ + p0q * 4);
        f32x4 v1 = *(const f32x4*)(s_ + (p0q ^ 1) * 4);
        union { bf16x8 h; uint32_t u[4]; } o;
        asm("v_cvt_pk_bf16_f32 %0, %1, %2" : "=v"(o.u[0]) : "v"(v0[0]), "v"(v0[1]));
        asm("v_cvt_pk_bf16_f32 %0, %1, %2" : "=v"(o.u[1]) : "v"(v0[2]), "v"(v0[3]));
        asm("v_cvt_pk_bf16_f32 %0, %1, %2" : "=v"(o.u[2]) : "v"(v1[0]), "v"(v1[1]));
        asm("v_cvt_pk_bf16_f32 %0, %1, %2" : "=v"(o.u[3]) : "v"(v1[2]), "v"(v1[3]));
        afr[m] = o.h;
      }
#pragma unroll
      for (int m = 0; m < 4; ++m)
#pragma unroll
        for (int n = 0; n < 4; ++n)
          acc[m][n] = __builtin_amdgcn_mfma_f32_16x16x32_bf16(afr[m], bfr[n], acc[m][n], 0, 0, 0);
    }
    __syncthreads();
  }

  // epilogue: C/D layout col = lane&15, row = (lane>>4)*4 + reg
  const int er0 = rowBase + wr * 64 + hi * 4;
  const int ec0 = colBase + wc * 64 + frow;
  float bv[4];
#pragma unroll
  for (int n = 0; n < 4; ++n) bv[n] = b1[ec0 + n * 16];
#pragma unroll
  for (int m = 0; m < 4; ++m)
#pragma unroll
    for (int n = 0; n < 4; ++n)
#pragma unroll
      for (int r = 0; r < 4; ++r) {
        float v = acc[m][n][r] + bv[n];
        v = v > 0.f ? v : expm1f(v);
        X[(size_t)(er0 + m * 16 + r) * DFC + ec0 + n * 16] = f2bf(v);
      }
}

// ---------------- K2: shape_params = x @ w_shape + b_shape -> d_out (mode | log_std) ----------------
__global__ __launch_bounds__(256)
void gemm2_kernel(const unsigned short* __restrict__ X, const float* __restrict__ Wsh,
                  const float* __restrict__ bsh, float* __restrict__ out) {
  __shared__ unsigned short sX[64 * 32];    // linear for global_load_lds
  __shared__ unsigned short sW[32 * 40];    // [j][k] stride 40 (80B)
  const int tid  = threadIdx.x;
  const int wave = tid >> 6, lane = tid & 63;
  const int rowB = blockIdx.x * 64;
  f32x4 acc[2] = {};
  const unsigned short* xp = X + (size_t)(rowB + (tid >> 2)) * DFC + (tid & 3) * 8;
  unsigned short* sXb = &sX[wave * 512];
  const int frow = lane & 15, fks = (lane >> 4) * 8;

  for (int kk = 0; kk < DFC; kk += 32) {
    gload_lds16(xp + kk, sXb);
    for (int idx = tid; idx < 32 * 40; idx += 256) {
      int j = idx / 40, ki = idx - j * 40;
      sW[idx] = (j < 20 && ki < 32) ? f2bf(Wsh[(size_t)(kk + ki) * 20 + j]) : (unsigned short)0;
    }
    __syncthreads();
    bf16x8 xa  = *(const bf16x8*)&sX[(wave * 16 + frow) * 32 + fks];
    bf16x8 w0  = *(const bf16x8*)&sW[(frow) * 40 + fks];
    bf16x8 w1f = *(const bf16x8*)&sW[(16 + frow) * 40 + fks];
    acc[0] = __builtin_amdgcn_mfma_f32_16x16x32_bf16(xa, w0,  acc[0], 0, 0, 0);
    acc[1] = __builtin_amdgcn_mfma_f32_16x16x32_bf16(xa, w1f, acc[1], 0, 0, 0);
    __syncthreads();
  }
  const int r0 = rowB + wave * 16 + (lane >> 4) * 4;
  const int c0 = lane & 15;
#pragma unroll
  for (int n = 0; n < 2; ++n) {
    int j = n * 16 + c0;
    if (j < 20) {
      float bj = bsh[j];
      int jj = j < 10 ? j : j - 10;
      size_t base = (j < 10) ? (size_t)0 : (size_t)B_ * NB_;
#pragma unroll
      for (int r = 0; r < 4; ++r)
        out[base + (size_t)(r0 + r) * NB_ + jj] = acc[n][r] + bj;
    }
  }
}

// ---------------- K3: samples = mode + exp(log_std) * noise ----------------
// one wave per row; float4 loads/stores; mode/exp(ls) broadcast from tiny LDS arrays.
__global__ __launch_bounds__(256)
void sample_kernel(const float* __restrict__ noise, float* __restrict__ out) {
  __shared__ float sm[4][NB_], se[4][NB_];
  const int tid  = threadIdx.x;
  const int wave = tid >> 6, lane = tid & 63;
  const int row  = blockIdx.x * 4 + wave;
  if (lane < NB_) {
    sm[wave][lane] = out[(size_t)row * NB_ + lane];
    se[wave][lane] = expf(out[(size_t)B_ * NB_ + (size_t)row * NB_ + lane]);
  }
  __syncthreads();
  const f32x4* np4 = (const f32x4*)(noise + (size_t)row * (S_ * NB_));
  f32x4*       op4 = (f32x4*)(out + (size_t)2 * B_ * NB_ + (size_t)row * (S_ * NB_));
#pragma unroll
  for (int it = 0; it < (S_ * NB_) / 256; ++it) {   // 10 iters
    f32x4 nv = np4[it * 64 + lane];
    int j0 = (lane * 4 + it * 6) % 10;
    int j1 = j0 + 1; if (j1 >= 10) j1 -= 10;
    int j2 = j1 + 1; if (j2 >= 10) j2 -= 10;
    int j3 = j2 + 1; if (j3 >= 10) j3 -= 10;
    f32x4 r;
    r[0] = sm[wave][j0] + se[wave][j0] * nv[0];
    r[1] = sm[wave][j1] + se[wave][j1] * nv[1];
    r[2] = sm[wave][j2] + se[wave][j2] * nv[2];
    r[3] = sm[wave][j3] + se[wave][j3] * nv[3];
    op4[it * 64 + lane] = r;
  }
}

extern "C" void kernel_launch(void* const* d_in, const int* in_sizes, int n_in,
                              void* d_out, int out_size, void* d_ws, size_t ws_size,
                              hipStream_t stream) {
  const float* A     = (const float*)d_in[0];  // [16384][2048]
  const float* W1    = (const float*)d_in[1];  // [2048][1024]
  const float* b1    = (const float*)d_in[2];  // [1024]
  const float* Wsh   = (const float*)d_in[3];  // [1024][20]
  const float* bsh   = (const float*)d_in[4];  // [20]
  const float* noise = (const float*)d_in[5];  // [16384][256][10]
  float* out = (float*)d_out;                  // mode | log_std | samples

  unsigned short* Wt = (unsigned short*)d_ws;                      // bf16 [1024][2048] = 4 MB
  unsigned short* X  = (unsigned short*)d_ws + (size_t)DFC * DIN;  // bf16 [16384][1024] = 33.5 MB

  convT_kernel<<<dim3(DFC / 32, DIN / 32), 256, 0, stream>>>(W1, Wt);
  gemm1_kernel<<<dim3((B_ / 128) * (DFC / 128)), 256, 0, stream>>>(A, Wt, b1, X);
  gemm2_kernel<<<dim3(B_ / 64), 256, 0, stream>>>(X, Wsh, bsh, out);
  sample_kernel<<<dim3(B_ / 4), 256, 0, stream>>>(noise, out);
}

// Round 8
// 223.676 us; speedup vs baseline: 1.1812x; 1.1812x over previous
//
#include <hip/hip_runtime.h>
#include <stdint.h>

using f32x4  = __attribute__((ext_vector_type(4))) float;
using bf16x8 = __attribute__((ext_vector_type(8))) short;
using ushort8 = __attribute__((ext_vector_type(8))) unsigned short;

#define B_   16384
#define S_   256
#define DIN  2048
#define DFC  1024
#define NB_  10

// f32 -> bf16 round-to-nearest-even
__device__ __forceinline__ unsigned short f2bf(float f) {
  union { float f; unsigned int u; } v; v.f = f;
  unsigned int u = v.u;
  unsigned int r = (u + 0x7FFFu + ((u >> 16) & 1u)) >> 16;
  return (unsigned short)r;
}

// async global->LDS, 16B per lane. LDS dest is wave-uniform base + lane*16.
__device__ __forceinline__ void gload_lds16(const void* g, void* l) {
  __builtin_amdgcn_global_load_lds(
      (const __attribute__((address_space(1))) unsigned int*)g,
      (__attribute__((address_space(3))) unsigned int*)l, 16, 0, 0);
}

// ---------------- K0a: W1 (f32, [K=2048][N=1024]) -> Wt (bf16, [N][K]) ----------------
__global__ __launch_bounds__(256)
void convT_kernel(const float* __restrict__ W, unsigned short* __restrict__ Wt) {
  __shared__ unsigned short t[32][33];
  const int tx = threadIdx.x & 31;
  const int ty = threadIdx.x >> 5;          // 0..7
  const int nb = blockIdx.x * 32;           // n base
  const int kb = blockIdx.y * 32;           // k base
#pragma unroll
  for (int i = 0; i < 32; i += 8)
    t[ty + i][tx] = f2bf(W[(size_t)(kb + ty + i) * DFC + nb + tx]);
  __syncthreads();
#pragma unroll
  for (int i = 0; i < 32; i += 8)
    Wt[(size_t)(nb + ty + i) * DIN + kb + tx] = t[tx][ty + i];
}

// ---------------- K0b: A (f32 [16384][2048]) -> Ab (bf16, same layout) ----------------
__global__ __launch_bounds__(256)
void convA_kernel(const float* __restrict__ A, unsigned short* __restrict__ Ab) {
  const size_t total = (size_t)B_ * DIN;
  size_t idx = ((size_t)blockIdx.x * 256 + threadIdx.x) * 8;
  const size_t stride = (size_t)gridDim.x * 256 * 8;
  for (; idx < total; idx += stride) {
    f32x4 a = *(const f32x4*)(A + idx);
    f32x4 b = *(const f32x4*)(A + idx + 4);
    ushort8 o;
    o[0] = f2bf(a[0]); o[1] = f2bf(a[1]); o[2] = f2bf(a[2]); o[3] = f2bf(a[3]);
    o[4] = f2bf(b[0]); o[5] = f2bf(b[1]); o[6] = f2bf(b[2]); o[7] = f2bf(b[3]);
    *(ushort8*)(Ab + idx) = o;
  }
}

// ---------------- K1: x = elu(Ab @ Wt^T + b1), stored bf16 ----------------
// 256x256 tile, 8 waves (2M x 4N). K split into 64 half-steps g of 32 (ring-4
// 16KB slices per operand). Per g: two phases.
//  alpha: {RD A(g,mq0)+B(g) | ST A(g+3)} -> BAR -> MFMA16(mq0)
//  beta : {RD A(g,mq1)      | ST B(g+3)} -> vmcnt(8) -> BAR -> MFMA16(mq1)
// Reads issue BEFORE the barrier, consumed after (LDS drains during barrier
// residence); vmcnt(8) = leave 4 stages in flight, proves slice g+1 staged
// before any wave reads it (template T3+T4 mechanism). Slice layout is r5's
// verified conflict-free XOR scheme (linear gload dest, inverse-swizzled src).
__global__ __launch_bounds__(512, 2)
void gemm1_kernel(const unsigned short* __restrict__ Ab, const unsigned short* __restrict__ Bt,
                  const float* __restrict__ b1, unsigned short* __restrict__ X) {
  __shared__ unsigned short sA4[4][8192];   // 64KB ring (A K-slices)
  __shared__ unsigned short sB4[4][8192];   // 64KB ring (B K-slices)
  const int tid  = threadIdx.x;
  const int wave = tid >> 6, lane = tid & 63;
  const int wm = wave >> 2, wn = wave & 3;      // 2M x 4N waves, wave tile 128x64
  const int b = blockIdx.x;                     // 256 blocks
  const int tile = (b & 7) * 32 + (b >> 3);     // XCD-chunked bijection
  const int mtile = tile >> 2, ntile = tile & 3;
  const int rowBase = mtile * 256, colBase = ntile * 256;

  f32x4 acc[8][4] = {};
  bf16x8 afr0[4], afr1[4], bfr[4];

  // staging source (inverse swizzle); one slice = 2 gload_lds per thread
  const int lrow0 = wave * 16 + (lane >> 3);
  const int q     = (lane & 7) ^ (lrow0 & 7);
  const unsigned short* gA = Ab + (size_t)(rowBase + lrow0 * 2 + (q >> 2)) * DIN + (q & 3) * 8;
  const unsigned short* gB = Bt + (size_t)(colBase + lrow0 * 2 + (q >> 2)) * DIN + (q & 3) * 8;
  const int ldOff = wave * 1024;

  // fragment read offsets
  const int frow = lane & 15, hi = lane >> 4, fr2 = frow >> 1;
  const int pp   = ((frow & 1) * 4 + hi) ^ fr2;
  const int aoff = (wm * 64 + fr2) * 64 + pp * 8;   // + h*2048 for m-quadrant
  const int boff = (wn * 32 + fr2) * 64 + pp * 8;

#define STA(kt, bu) do { const unsigned short* g_ = gA + (kt) * 32;             \
    gload_lds16(g_, &sA4[bu][ldOff]);                                           \
    gload_lds16(g_ + (size_t)16 * DIN, &sA4[bu][ldOff + 512]); } while (0)
#define STB(kt, bu) do { const unsigned short* g_ = gB + (kt) * 32;             \
    gload_lds16(g_, &sB4[bu][ldOff]);                                           \
    gload_lds16(g_ + (size_t)16 * DIN, &sB4[bu][ldOff + 512]); } while (0)
#define RDA(bu, h, dst) do { const unsigned short* s_ = &sA4[bu][aoff + (h) * 2048]; \
    dst[0] = *(const bf16x8*)(s_);        dst[1] = *(const bf16x8*)(s_ + 512);  \
    dst[2] = *(const bf16x8*)(s_ + 1024); dst[3] = *(const bf16x8*)(s_ + 1536); } while (0)
#define RDB(bu, dst) do { const unsigned short* s_ = &sB4[bu][boff];            \
    dst[0] = *(const bf16x8*)(s_);        dst[1] = *(const bf16x8*)(s_ + 512);  \
    dst[2] = *(const bf16x8*)(s_ + 1024); dst[3] = *(const bf16x8*)(s_ + 1536); } while (0)
#define MM16(h, Ar, Br) do { __builtin_amdgcn_s_setprio(1);                     \
    _Pragma("unroll") for (int m_ = 0; m_ < 4; ++m_)                            \
    _Pragma("unroll") for (int n_ = 0; n_ < 4; ++n_)                            \
      acc[(h) * 4 + m_][n_] = __builtin_amdgcn_mfma_f32_16x16x32_bf16(          \
          Ar[m_], Br[n_], acc[(h) * 4 + m_][n_], 0, 0, 0);                      \
    __builtin_amdgcn_s_setprio(0); } while (0)
#define VMW(N) asm volatile("s_waitcnt vmcnt(" #N ")" ::: "memory")
#define FENCE asm volatile("" ::: "memory")
#define BAR do { FENCE; __builtin_amdgcn_s_barrier(); FENCE; } while (0)

  // prologue: stage slices 0..2 both ops; prove slice 0 complete; enter loop
  STA(0, 0); STB(0, 0); STA(1, 1); STB(1, 1); STA(2, 2); STB(2, 2);
  VMW(8);
  BAR;

#pragma unroll 4
  for (int g = 0; g <= 60; ++g) {
    const int s = g & 3, sn = (g + 3) & 3;
    // alpha(g)
    RDA(s, 0, afr0); RDB(s, bfr);
    STA(g + 3, sn);
    BAR;
    MM16(0, afr0, bfr);
    // beta(g)
    RDA(s, 1, afr1);
    STB(g + 3, sn);
    VMW(8);
    BAR;
    MM16(1, afr1, bfr);
  }
  // g = 61
  RDA(1, 0, afr0); RDB(1, bfr); BAR; MM16(0, afr0, bfr);
  RDA(1, 1, afr1); VMW(4); BAR; MM16(1, afr1, bfr);
  // g = 62
  RDA(2, 0, afr0); RDB(2, bfr); BAR; MM16(0, afr0, bfr);
  RDA(2, 1, afr1); VMW(0); BAR; MM16(1, afr1, bfr);
  // g = 63
  RDA(3, 0, afr0); RDB(3, bfr); BAR; MM16(0, afr0, bfr);
  RDA(3, 1, afr1); BAR; MM16(1, afr1, bfr);
#undef STA
#undef STB
#undef RDA
#undef RDB
#undef MM16

  // epilogue: C/D layout col = lane&15, row = (lane>>4)*4 + reg
  const int er0 = rowBase + wm * 128 + hi * 4;
  const int ec0 = colBase + wn * 64 + frow;
  float bv[4];
#pragma unroll
  for (int n = 0; n < 4; ++n) bv[n] = b1[ec0 + n * 16];
#pragma unroll
  for (int m = 0; m < 8; ++m)
#pragma unroll
    for (int n = 0; n < 4; ++n)
#pragma unroll
      for (int r = 0; r < 4; ++r) {
        float v = acc[m][n][r] + bv[n];
        v = v > 0.f ? v : expm1f(v);
        X[(size_t)(er0 + m * 16 + r) * DFC + ec0 + n * 16] = f2bf(v);
      }
}

// ---------------- K2: shape_params = x @ w_shape + b_shape -> d_out (mode | log_std) ----------------
__global__ __launch_bounds__(256)
void gemm2_kernel(const unsigned short* __restrict__ X, const float* __restrict__ Wsh,
                  const float* __restrict__ bsh, float* __restrict__ out) {
  __shared__ unsigned short sX[64 * 32];    // linear for global_load_lds
  __shared__ unsigned short sW[32 * 40];    // [j][k] stride 40 (80B)
  const int tid  = threadIdx.x;
  const int wave = tid >> 6, lane = tid & 63;
  const int rowB = blockIdx.x * 64;
  f32x4 acc[2] = {};
  const unsigned short* xp = X + (size_t)(rowB + (tid >> 2)) * DFC + (tid & 3) * 8;
  unsigned short* sXb = &sX[wave * 512];
  const int frow = lane & 15, fks = (lane >> 4) * 8;

  for (int kk = 0; kk < DFC; kk += 32) {
    gload_lds16(xp + kk, sXb);
    for (int idx = tid; idx < 32 * 40; idx += 256) {
      int j = idx / 40, ki = idx - j * 40;
      sW[idx] = (j < 20 && ki < 32) ? f2bf(Wsh[(size_t)(kk + ki) * 20 + j]) : (unsigned short)0;
    }
    __syncthreads();
    bf16x8 xa  = *(const bf16x8*)&sX[(wave * 16 + frow) * 32 + fks];
    bf16x8 w0  = *(const bf16x8*)&sW[(frow) * 40 + fks];
    bf16x8 w1f = *(const bf16x8*)&sW[(16 + frow) * 40 + fks];
    acc[0] = __builtin_amdgcn_mfma_f32_16x16x32_bf16(xa, w0,  acc[0], 0, 0, 0);
    acc[1] = __builtin_amdgcn_mfma_f32_16x16x32_bf16(xa, w1f, acc[1], 0, 0, 0);
    __syncthreads();
  }
  const int r0 = rowB + wave * 16 + (lane >> 4) * 4;
  const int c0 = lane & 15;
#pragma unroll
  for (int n = 0; n < 2; ++n) {
    int j = n * 16 + c0;
    if (j < 20) {
      float bj = bsh[j];
      int jj = j < 10 ? j : j - 10;
      size_t base = (j < 10) ? (size_t)0 : (size_t)B_ * NB_;
#pragma unroll
      for (int r = 0; r < 4; ++r)
        out[base + (size_t)(r0 + r) * NB_ + jj] = acc[n][r] + bj;
    }
  }
}

// ---------------- K3: samples = mode + exp(log_std) * noise ----------------
// one wave per row; float4 loads/stores; mode/exp(ls) broadcast from tiny LDS arrays.
__global__ __launch_bounds__(256)
void sample_kernel(const float* __restrict__ noise, float* __restrict__ out) {
  __shared__ float sm[4][NB_], se[4][NB_];
  const int tid  = threadIdx.x;
  const int wave = tid >> 6, lane = tid & 63;
  const int row  = blockIdx.x * 4 + wave;
  if (lane < NB_) {
    sm[wave][lane] = out[(size_t)row * NB_ + lane];
    se[wave][lane] = expf(out[(size_t)B_ * NB_ + (size_t)row * NB_ + lane]);
  }
  __syncthreads();
  const f32x4* np4 = (const f32x4*)(noise + (size_t)row * (S_ * NB_));
  f32x4*       op4 = (f32x4*)(out + (size_t)2 * B_ * NB_ + (size_t)row * (S_ * NB_));
#pragma unroll
  for (int it = 0; it < (S_ * NB_) / 256; ++it) {   // 10 iters
    f32x4 nv = np4[it * 64 + lane];
    int j0 = (lane * 4 + it * 6) % 10;
    int j1 = j0 + 1; if (j1 >= 10) j1 -= 10;
    int j2 = j1 + 1; if (j2 >= 10) j2 -= 10;
    int j3 = j2 + 1; if (j3 >= 10) j3 -= 10;
    f32x4 r;
    r[0] = sm[wave][j0] + se[wave][j0] * nv[0];
    r[1] = sm[wave][j1] + se[wave][j1] * nv[1];
    r[2] = sm[wave][j2] + se[wave][j2] * nv[2];
    r[3] = sm[wave][j3] + se[wave][j3] * nv[3];
    op4[it * 64 + lane] = r;
  }
}

extern "C" void kernel_launch(void* const* d_in, const int* in_sizes, int n_in,
                              void* d_out, int out_size, void* d_ws, size_t ws_size,
                              hipStream_t stream) {
  const float* A     = (const float*)d_in[0];  // [16384][2048]
  const float* W1    = (const float*)d_in[1];  // [2048][1024]
  const float* b1    = (const float*)d_in[2];  // [1024]
  const float* Wsh   = (const float*)d_in[3];  // [1024][20]
  const float* bsh   = (const float*)d_in[4];  // [20]
  const float* noise = (const float*)d_in[5];  // [16384][256][10]
  float* out = (float*)d_out;                  // mode | log_std | samples

  unsigned short* Wt = (unsigned short*)d_ws;                      // bf16 [1024][2048] = 4 MB
  unsigned short* X  = (unsigned short*)d_ws + (size_t)DFC * DIN;  // bf16 [16384][1024] = 33.5 MB
  // Ab (bf16 A, 64 MB): ws if it fits, else stash in d_out's samples region
  // (written before gemm1 reads it, overwritten by sample_kernel at the end).
  const size_t wsNeed = (size_t)DFC * DIN * 2 + (size_t)B_ * DFC * 2 + (size_t)B_ * DIN * 2;
  unsigned short* Ab = (ws_size >= wsNeed)
      ? (unsigned short*)d_ws + (size_t)DFC * DIN + (size_t)B_ * DFC
      : (unsigned short*)(out + (size_t)2 * B_ * NB_);

  convT_kernel<<<dim3(DFC / 32, DIN / 32), 256, 0, stream>>>(W1, Wt);
  convA_kernel<<<dim3(2048), 256, 0, stream>>>(A, Ab);
  gemm1_kernel<<<dim3((B_ / 256) * (DFC / 256)), 512, 0, stream>>>(Ab, Wt, b1, X);
  gemm2_kernel<<<dim3(B_ / 64), 256, 0, stream>>>(X, Wsh, bsh, out);
  sample_kernel<<<dim3(B_ / 4), 256, 0, stream>>>(noise, out);
}